// Round 3
// baseline (163.202 us; speedup 1.0000x reference)
//
#include <hip/hip_runtime.h>

// LBP block — single fused kernel.
// block = (n, 4-row tile, group of 8 output channels), 256 threads (4 waves).
// Phase 0: stage x tile (6 rows x 3 ch) into LDS once; og==0 blocks also
//          emit the x-copy channels (out[:,0:3]) from the staging registers.
// Loop over 8 channels o: y rows from x-LDS into y-LDS (each y value
//          computed exactly once), then 8-neighbor heaviside compares
//          weighted by exp(w), float4 store.
//
// Numerics (do not change): y = (x0*cw0 + x1*cw1) + x2*cw2 sequentially with
// FMA contraction OFF to match the numpy reference; (c - s > 0) == (c > s)
// exactly for finite floats; y has a single computation site so all
// consumers compare identical bits.

__global__ __launch_bounds__(256) void lbp_all(
    const float* __restrict__ x,
    const float* __restrict__ conv_w,
    const float* __restrict__ w,
    float* __restrict__ out)
{
#pragma clang fp contract(off)
    const int n    = blockIdx.z;
    const int og   = blockIdx.y;          // channel group: o = og*8 .. og*8+7
    const int h0   = blockIdx.x * 4;      // 4 output rows per block
    const int tid  = threadIdx.x;
    const int lane = tid & 63;
    const int wv   = tid >> 6;            // wave 0..3
    const int col  = lane * 4;

    __shared__ float xs[6][3][256];       // x rows h0-1 .. h0+4 (clamped), 3 ch
    __shared__ float ys[6][256];          // y rows for current o
    __shared__ float ews[64];             // exp(w) for this block's 8 channels

    if (tid < 64) ews[tid] = expf(w[og * 64 + tid]);

    const float* xn = x + (size_t)n * 3 * 256 * 256;

    // ---- Phase 0: stage x tile; og==0 also writes the copy channels ----
    #pragma unroll
    for (int p = 0; p < 5; ++p) {
        const int u = wv + 4 * p;         // 18 (row,ch) units
        if (u < 18) {
            const int r  = u / 3;
            const int ch = u % 3;
            int row = h0 - 1 + r;
            row = row < 0 ? 0 : (row > 255 ? 255 : row);
            const float4 v = *(const float4*)(xn + ((ch * 256 + row) * 256 + col));
            *(float4*)&xs[r][ch][col] = v;
            if (og == 0 && r >= 1 && r <= 4) {
                *(float4*)(out + ((((size_t)n * 67 + ch) * 256 + (h0 + r - 1)) * 256 + col)) = v;
            }
        }
    }
    __syncthreads();

    // ---- Channel loop ----
    for (int oi = 0; oi < 8; ++oi) {
        const int o = og * 8 + oi;
        const float cw0 = conv_w[o * 3 + 0];
        const float cw1 = conv_w[o * 3 + 1];
        const float cw2 = conv_w[o * 3 + 2];

        // y rows 0..5 into LDS (one computation site per y value)
        #pragma unroll
        for (int p = 0; p < 2; ++p) {
            const int r = wv + 4 * p;
            if (r < 6) {
                const float4 a = *(const float4*)&xs[r][0][col];
                const float4 b = *(const float4*)&xs[r][1][col];
                const float4 c = *(const float4*)&xs[r][2][col];
                float4 yv;
                yv.x = a.x * cw0 + b.x * cw1 + c.x * cw2;
                yv.y = a.y * cw0 + b.y * cw1 + c.y * cw2;
                yv.z = a.z * cw0 + b.z * cw1 + c.z * cw2;
                yv.w = a.w * cw0 + b.w * cw1 + c.w * cw2;
                *(float4*)&ys[r][col] = yv;
            }
        }
        __syncthreads();

        // compares: wave wv owns output row h0+wv
        // Y[r][k] = y at LDS row (wv+r), col (col-1+k); halo via shuffles,
        // lane-0/63 halo garbage feeds only border pixels (zeroed).
        float Y[3][6];
        #pragma unroll
        for (int r = 0; r < 3; ++r) {
            const float4 v = *(const float4*)&ys[wv + r][col];
            Y[r][1] = v.x; Y[r][2] = v.y; Y[r][3] = v.z; Y[r][4] = v.w;
            Y[r][0] = __shfl_up(v.w, 1);
            Y[r][5] = __shfl_down(v.x, 1);
        }

        const float e0 = ews[oi * 8 + 0], e1 = ews[oi * 8 + 1];
        const float e2 = ews[oi * 8 + 2], e3 = ews[oi * 8 + 3];
        const float e4 = ews[oi * 8 + 4], e5 = ews[oi * 8 + 5];
        const float e6 = ews[oi * 8 + 6], e7 = ews[oi * 8 + 7];

        const int hrow = h0 + wv;
        float res[4];
        if (hrow == 0 || hrow == 255) {
            res[0] = res[1] = res[2] = res[3] = 0.f;
        } else {
            #pragma unroll
            for (int j = 0; j < 4; ++j) {
                const int cidx = col + j;
                if ((cidx == 0) | (cidx == 255)) { res[j] = 0.f; continue; }
                const float c = Y[1][j + 1];
                float acc;
                acc  = (c > Y[0][j    ]) ? e0 : 0.f;   // (-1,-1)
                acc += (c > Y[0][j + 1]) ? e1 : 0.f;   // (-1, 0)
                acc += (c > Y[0][j + 2]) ? e2 : 0.f;   // (-1,+1)
                acc += (c > Y[1][j    ]) ? e3 : 0.f;   // ( 0,-1)
                acc += (c > Y[2][j    ]) ? e4 : 0.f;   // (+1,-1)
                acc += (c > Y[2][j + 1]) ? e5 : 0.f;   // (+1, 0)
                acc += (c > Y[2][j + 2]) ? e6 : 0.f;   // (+1,+1)
                acc += (c > Y[1][j + 2]) ? e7 : 0.f;   // ( 0,+1)
                res[j] = acc;
            }
        }
        *(float4*)(out + ((((size_t)n * 67 + 3 + o) * 256 + hrow) * 256 + col)) =
            make_float4(res[0], res[1], res[2], res[3]);

        __syncthreads();   // protect ys before next o overwrites it
    }
}

extern "C" void kernel_launch(void* const* d_in, const int* in_sizes, int n_in,
                              void* d_out, int out_size, void* d_ws, size_t ws_size,
                              hipStream_t stream) {
    const float* x      = (const float*)d_in[0];
    const float* conv_w = (const float*)d_in[1];
    const float* w      = (const float*)d_in[2];
    float* out          = (float*)d_out;

    dim3 grid(64, 8, 8);   // (4-row tiles, channel groups of 8, batch)
    dim3 block(256);
    hipLaunchKernelGGL(lbp_all, grid, block, 0, stream, x, conv_w, w, out);
}

// Round 4
// 154.137 us; speedup vs baseline: 1.0588x; 1.0588x over previous
//
#include <hip/hip_runtime.h>

// LBP block — single fused, barrier-light kernel.
// block = (n, 4-row tile, group of 16 output channels), 256 threads (4 waves).
// Each wave owns ONE output row and is self-sufficient: its 3 x-rows x 3
// input channels live in 9 float4 registers; the 16-channel loop is pure
// register VALU (y recompute per wave — bit-identical across waves since the
// contract-off expression and inputs are identical). Halo columns via shfl.
// One __syncthreads total (exp(w) LDS table). og==0 blocks also emit the
// x-copy channels from the registers already loaded.
//
// Numerics (do not change): y = (x0*cw0 + x1*cw1) + x2*cw2 sequentially with
// FMA contraction OFF to match the numpy reference; (c - s > 0) == (c > s)
// exactly for finite floats.

__global__ __launch_bounds__(256) void lbp_all(
    const float* __restrict__ x,
    const float* __restrict__ conv_w,
    const float* __restrict__ w,
    float* __restrict__ out)
{
#pragma clang fp contract(off)
    const int n    = blockIdx.z;
    const int og   = blockIdx.y;          // channels og*16 .. og*16+15
    const int h0   = blockIdx.x * 4;      // 4 output rows per block
    const int tid  = threadIdx.x;
    const int lane = tid & 63;
    const int wv   = tid >> 6;            // wave 0..3 -> output row h0+wv
    const int col  = lane * 4;
    const int hrow = h0 + wv;

    __shared__ float ews[128];            // exp(w) for this block's 16 channels
    if (tid < 128) ews[tid] = expf(w[og * 128 + tid]);

    const float* xn = x + (size_t)n * 3 * 65536;

    // x rows hrow-1..hrow+1 (clamped), 3 input channels, in registers.
    float4 xr[3][3];
    #pragma unroll
    for (int r = 0; r < 3; ++r) {
        int row = hrow - 1 + r;
        row = row < 0 ? 0 : (row > 255 ? 255 : row);
        #pragma unroll
        for (int ch = 0; ch < 3; ++ch)
            xr[r][ch] = *(const float4*)(xn + (ch * 256 + row) * 256 + col);
    }

    if (og == 0) {  // copy channels 0..2 (middle row is exactly row hrow)
        #pragma unroll
        for (int ch = 0; ch < 3; ++ch)
            *(float4*)(out + ((((size_t)n * 67 + ch) * 256 + hrow) * 256 + col)) = xr[1][ch];
    }

    __syncthreads();

    float* obase = out + ((((size_t)n * 67 + 3 + og * 16) * 256 + hrow) * 256 + col);

    if (hrow == 0 || hrow == 255) {       // border rows: zeros for all channels
        const float4 z = make_float4(0.f, 0.f, 0.f, 0.f);
        #pragma unroll
        for (int oi = 0; oi < 16; ++oi)
            *(float4*)(obase + (size_t)oi * 65536) = z;
        return;
    }

    #pragma unroll 2
    for (int oi = 0; oi < 16; ++oi) {
        const int o = og * 16 + oi;
        const float cw0 = conv_w[o * 3 + 0];
        const float cw1 = conv_w[o * 3 + 1];
        const float cw2 = conv_w[o * 3 + 2];

        // Y[r][k] = y at row hrow-1+r, col (col-1+k), k=0..5; halo via shfl.
        float Y[3][6];
        #pragma unroll
        for (int r = 0; r < 3; ++r) {
            float4 yv;
            yv.x = xr[r][0].x * cw0 + xr[r][1].x * cw1 + xr[r][2].x * cw2;
            yv.y = xr[r][0].y * cw0 + xr[r][1].y * cw1 + xr[r][2].y * cw2;
            yv.z = xr[r][0].z * cw0 + xr[r][1].z * cw1 + xr[r][2].z * cw2;
            yv.w = xr[r][0].w * cw0 + xr[r][1].w * cw1 + xr[r][2].w * cw2;
            Y[r][1] = yv.x; Y[r][2] = yv.y; Y[r][3] = yv.z; Y[r][4] = yv.w;
            Y[r][0] = __shfl_up(yv.w, 1);   // lane 0 garbage -> col 0 zeroed
            Y[r][5] = __shfl_down(yv.x, 1); // lane 63 garbage -> col 255 zeroed
        }

        const float e0 = ews[oi * 8 + 0], e1 = ews[oi * 8 + 1];
        const float e2 = ews[oi * 8 + 2], e3 = ews[oi * 8 + 3];
        const float e4 = ews[oi * 8 + 4], e5 = ews[oi * 8 + 5];
        const float e6 = ews[oi * 8 + 6], e7 = ews[oi * 8 + 7];

        float res[4];
        #pragma unroll
        for (int j = 0; j < 4; ++j) {
            const float c = Y[1][j + 1];
            float acc;
            acc  = (c > Y[0][j    ]) ? e0 : 0.f;   // (-1,-1)
            acc += (c > Y[0][j + 1]) ? e1 : 0.f;   // (-1, 0)
            acc += (c > Y[0][j + 2]) ? e2 : 0.f;   // (-1,+1)
            acc += (c > Y[1][j    ]) ? e3 : 0.f;   // ( 0,-1)
            acc += (c > Y[2][j    ]) ? e4 : 0.f;   // (+1,-1)
            acc += (c > Y[2][j + 1]) ? e5 : 0.f;   // (+1, 0)
            acc += (c > Y[2][j + 2]) ? e6 : 0.f;   // (+1,+1)
            acc += (c > Y[1][j + 2]) ? e7 : 0.f;   // ( 0,+1)
            res[j] = acc;
        }
        if (lane == 0)  res[0] = 0.f;   // col 0
        if (lane == 63) res[3] = 0.f;   // col 255

        *(float4*)(obase + (size_t)oi * 65536) =
            make_float4(res[0], res[1], res[2], res[3]);
    }
}

extern "C" void kernel_launch(void* const* d_in, const int* in_sizes, int n_in,
                              void* d_out, int out_size, void* d_ws, size_t ws_size,
                              hipStream_t stream) {
    const float* x      = (const float*)d_in[0];
    const float* conv_w = (const float*)d_in[1];
    const float* w      = (const float*)d_in[2];
    float* out          = (float*)d_out;

    dim3 grid(64, 4, 8);   // (4-row tiles, channel groups of 16, batch)
    dim3 block(256);
    hipLaunchKernelGGL(lbp_all, grid, block, 0, stream, x, conv_w, w, out);
}

// Round 5
// 151.999 us; speedup vs baseline: 1.0737x; 1.0141x over previous
//
#include <hip/hip_runtime.h>

// LBP block — single fused kernel, 2 output rows per wave.
// block = 256 threads (4 waves) = (n, 8-row tile, group of 16 channels).
// Each wave owns rows hrow0, hrow0+1 and is self-sufficient: its 4 x-rows x 3
// input channels live in 12 float4 registers; the 16-channel loop is pure
// register VALU + 8 shuffles (4 y-rows serve 2 output rows -> 2x redundancy
// instead of 3x). y recompute across waves is bit-identical (same contract-off
// expression, same inputs). One __syncthreads total (exp(w) table).
// og==0 blocks also emit the x-copy channels from already-loaded registers.
//
// Numerics (do not change): y = (x0*cw0 + x1*cw1) + x2*cw2 sequentially with
// FMA contraction OFF to match the numpy reference; (c - s > 0) == (c > s)
// exactly for finite floats.

__global__ __launch_bounds__(256) void lbp_all(
    const float* __restrict__ x,
    const float* __restrict__ conv_w,
    const float* __restrict__ w,
    float* __restrict__ out)
{
#pragma clang fp contract(off)
    const int n     = blockIdx.z;
    const int og    = blockIdx.y;            // channels og*16 .. og*16+15
    const int tid   = threadIdx.x;
    const int lane  = tid & 63;
    const int wv    = tid >> 6;              // wave 0..3
    const int col   = lane * 4;
    const int hrow0 = blockIdx.x * 8 + wv * 2;   // wave's first output row

    __shared__ float ews[128];               // exp(w) for this block's 16 ch
    if (tid < 128) ews[tid] = expf(w[og * 128 + tid]);

    const float* xn = x + (size_t)n * 3 * 65536;

    // x rows hrow0-1 .. hrow0+2 (clamped), 3 input channels, in registers.
    float4 xr[4][3];
    #pragma unroll
    for (int r = 0; r < 4; ++r) {
        int row = hrow0 - 1 + r;
        row = row < 0 ? 0 : (row > 255 ? 255 : row);
        #pragma unroll
        for (int ch = 0; ch < 3; ++ch)
            xr[r][ch] = *(const float4*)(xn + (ch * 256 + row) * 256 + col);
    }

    if (og == 0) {  // copy channels 0..2; xr[1]=row hrow0, xr[2]=row hrow0+1
        #pragma unroll
        for (int ch = 0; ch < 3; ++ch) {
            float* cp = out + ((((size_t)n * 67 + ch) * 256 + hrow0) * 256 + col);
            *(float4*)cp         = xr[1][ch];
            *(float4*)(cp + 256) = xr[2][ch];
        }
    }

    __syncthreads();

    float* obase = out + ((((size_t)n * 67 + 3 + og * 16) * 256 + hrow0) * 256 + col);

    #pragma unroll 4
    for (int oi = 0; oi < 16; ++oi) {
        const int o = og * 16 + oi;
        const float cw0 = conv_w[o * 3 + 0];
        const float cw1 = conv_w[o * 3 + 1];
        const float cw2 = conv_w[o * 3 + 2];

        // Y[r][k] = y at row hrow0-1+r, col (col-1+k), k=0..5; halo via shfl.
        float Y[4][6];
        #pragma unroll
        for (int r = 0; r < 4; ++r) {
            float4 yv;
            yv.x = xr[r][0].x * cw0 + xr[r][1].x * cw1 + xr[r][2].x * cw2;
            yv.y = xr[r][0].y * cw0 + xr[r][1].y * cw1 + xr[r][2].y * cw2;
            yv.z = xr[r][0].z * cw0 + xr[r][1].z * cw1 + xr[r][2].z * cw2;
            yv.w = xr[r][0].w * cw0 + xr[r][1].w * cw1 + xr[r][2].w * cw2;
            Y[r][1] = yv.x; Y[r][2] = yv.y; Y[r][3] = yv.z; Y[r][4] = yv.w;
            Y[r][0] = __shfl_up(yv.w, 1);   // lane 0 garbage -> col 0 zeroed
            Y[r][5] = __shfl_down(yv.x, 1); // lane 63 garbage -> col 255 zeroed
        }

        const float e0 = ews[oi * 8 + 0], e1 = ews[oi * 8 + 1];
        const float e2 = ews[oi * 8 + 2], e3 = ews[oi * 8 + 3];
        const float e4 = ews[oi * 8 + 4], e5 = ews[oi * 8 + 5];
        const float e6 = ews[oi * 8 + 6], e7 = ews[oi * 8 + 7];

        #pragma unroll
        for (int k = 0; k < 2; ++k) {        // the wave's two output rows
            const int hrow = hrow0 + k;
            float res[4];
            if (hrow == 0 || hrow == 255) {  // wave-uniform branch
                res[0] = res[1] = res[2] = res[3] = 0.f;
            } else {
                const float* up  = Y[k];
                const float* mid = Y[k + 1];
                const float* dn  = Y[k + 2];
                #pragma unroll
                for (int j = 0; j < 4; ++j) {
                    const float c = mid[j + 1];
                    float acc;
                    acc  = (c > up [j    ]) ? e0 : 0.f;   // (-1,-1)
                    acc += (c > up [j + 1]) ? e1 : 0.f;   // (-1, 0)
                    acc += (c > up [j + 2]) ? e2 : 0.f;   // (-1,+1)
                    acc += (c > mid[j    ]) ? e3 : 0.f;   // ( 0,-1)
                    acc += (c > dn [j    ]) ? e4 : 0.f;   // (+1,-1)
                    acc += (c > dn [j + 1]) ? e5 : 0.f;   // (+1, 0)
                    acc += (c > dn [j + 2]) ? e6 : 0.f;   // (+1,+1)
                    acc += (c > mid[j + 2]) ? e7 : 0.f;   // ( 0,+1)
                    res[j] = acc;
                }
                if (lane == 0)  res[0] = 0.f;   // col 0
                if (lane == 63) res[3] = 0.f;   // col 255
            }
            *(float4*)(obase + (size_t)oi * 65536 + (size_t)k * 256) =
                make_float4(res[0], res[1], res[2], res[3]);
        }
    }
}

extern "C" void kernel_launch(void* const* d_in, const int* in_sizes, int n_in,
                              void* d_out, int out_size, void* d_ws, size_t ws_size,
                              hipStream_t stream) {
    const float* x      = (const float*)d_in[0];
    const float* conv_w = (const float*)d_in[1];
    const float* w      = (const float*)d_in[2];
    float* out          = (float*)d_out;

    dim3 grid(32, 4, 8);   // (8-row tiles, channel groups of 16, batch)
    dim3 block(256);
    hipLaunchKernelGGL(lbp_all, grid, block, 0, stream, x, conv_w, w, out);
}